// Round 3
// baseline (1021.569 us; speedup 1.0000x reference)
//
#include <hip/hip_runtime.h>

constexpr int G = 64;
constexpr int C = 16;
constexpr int NBATCH = 4;
constexpr int HID = 96;
constexpr int G3 = G * G * G; // 262144 = 2^18

// ---------------------------------------------------------------------------
// Pass 1: perception (edge-padded sobel stencil) + fused MLP + stochastic
// update.
//
// R3 change: the MLP was K$-thrash-bound. w1 (24.6 KB) + w2 (6 KB) were
// streamed as wave-uniform s_loads by every wave, every y-iteration; w1
// exceeds the per-CU scalar cache so all resident waves missed to L2 each
// pass (VALUBusy pinned at 25% despite 47% occupancy). Weights now live in
// LDS (w2 transposed to [y][c]) and are read as same-address ds_read_b128
// broadcasts — conflict-free and ~2 cyc vs an L2-latency scalar miss.
// Halo tile re-strided to 12/row, 120/plane: the wave's 64 stencil addresses
// become exactly 2 lanes/bank (free) instead of 3-way conflicts.
// One 8x8x8 voxel tile per block, 512 threads, 1 voxel/thread.
// ---------------------------------------------------------------------------
constexpr int W1_F = HID * 64;   // 6144 floats
constexpr int W2_F = HID * 16;   // 1536 floats, transposed [y][c]
constexpr int SY = 12;           // halo row stride (perfect 2-way banks)
constexpr int SZ = 120;          // halo plane stride
constexpr int TILE_F = 10 * SZ;  // 1200

__global__ __launch_bounds__(512, 4)
void nca_update(const float* __restrict__ state, const float* __restrict__ rand_u,
                const float* __restrict__ w1, const float* __restrict__ b1,
                const float* __restrict__ w2,
                float* __restrict__ out, float* __restrict__ premask)
{
    __shared__ float lw1[W1_F];      // 24576 B
    __shared__ float lb1[HID];       //   384 B
    __shared__ float lw2t[W2_F];     //  6144 B
    __shared__ float tile[2][TILE_F];//  9600 B   -> 40.7 KB total

    const int tid = threadIdx.x;
    const int bid = blockIdx.x;
    const int bx = bid & 7, by = (bid >> 3) & 7, bz = (bid >> 6) & 7, n = bid >> 9;
    const int x0 = bx * 8, y0 = by * 8, z0 = bz * 8;
    const float* sb = state + (size_t)n * C * G3;

    // --- one-time weight staging (coalesced; w1/w2 are L2-resident) ---
    for (int i = tid; i < W1_F; i += 512) lw1[i] = w1[i];
    if (tid < HID) lb1[tid] = b1[tid];
    for (int i = tid; i < W2_F; i += 512) lw2t[i] = w2[(i & 15) * HID + (i >> 4)];

    // --- halo source offsets + LDS targets (identical every channel) ---
    const int i0 = tid;
    const int i1 = tid + 512;
    const bool wr1 = (i1 < 1000);
    int vo0, vo1, s0i, s1i;
    {
        int lx = i0 % 10, t = i0 / 10;
        int ly = t % 10, lz = t / 10;
        s0i = lz * SZ + ly * SY + lx;
        int gx = min(max(x0 + lx - 1, 0), G - 1);
        int gy = min(max(y0 + ly - 1, 0), G - 1);
        int gz = min(max(z0 + lz - 1, 0), G - 1);
        vo0 = gz * (G * G) + gy * G + gx;
    }
    {
        int j = min(i1, 999);
        int lx = j % 10, t = j / 10;
        int ly = t % 10, lz = t / 10;
        s1i = lz * SZ + ly * SY + lx;
        int gx = min(max(x0 + lx - 1, 0), G - 1);
        int gy = min(max(y0 + ly - 1, 0), G - 1);
        int gz = min(max(z0 + lz - 1, 0), G - 1);
        vo1 = gz * (G * G) + gy * G + gx;
    }

    // Per-voxel rand load issued early; consumed only at the end.
    const int lxl = (tid & 7) + 1, lyl = ((tid >> 3) & 7) + 1, lzl = (tid >> 6) + 1;
    const int gx = x0 + lxl - 1, gy = y0 + lyl - 1, gz = z0 + lzl - 1;
    const size_t vofs = (size_t)gz * (G * G) + (size_t)gy * G + gx;
    const float ru = rand_u[(size_t)n * G3 + vofs];

    // Stage channel 0.
    tile[0][s0i] = sb[vo0];
    if (wr1) tile[0][s1i] = sb[vo1];
    __syncthreads(); // also covers weight staging

    const int cbase = (lzl - 1) * SZ + (lyl - 1) * SY + (lxl - 1);

    // Perception features; layout matches w1 columns: x = k*16 + c.
    float p[64];
    float amax = -3.0e38f;

#pragma unroll
    for (int c = 0; c < C; ++c) {
        // Prefetch next channel (HBM latency hides under the stencil).
        float r0 = 0.f, r1 = 0.f;
        if (c + 1 < C) {
            r0 = sb[(size_t)(c + 1) * G3 + vo0];
            r1 = sb[(size_t)(c + 1) * G3 + vo1];
        }

        const float* buf = tile[c & 1];
        float P0 = 0.f, P2 = 0.f, U0 = 0.f, U2 = 0.f, V0 = 0.f, V2 = 0.f;
        float ctr = 0.f, mx = -3.0e38f;
#pragma unroll
        for (int dz = 0; dz < 3; ++dz) {
            const float gzw = (dz == 1) ? 2.f : 1.f;
#pragma unroll
            for (int dy = 0; dy < 3; ++dy) {
                const float gyw = (dy == 1) ? 2.f : 1.f;
                const float* r = buf + cbase + dz * SZ + dy * SY;
                const float a0 = r[0], a1 = r[1], a2 = r[2];
                const float rs = a0 + 2.f * a1 + a2;
                if (dz == 0) P0 += gyw * rs;
                if (dz == 2) P2 += gyw * rs;
                if (dy == 0) U0 += gzw * rs;
                if (dy == 2) U2 += gzw * rs;
                V0 += gzw * gyw * a0;
                V2 += gzw * gyw * a2;
                if (dz == 1 && dy == 1) ctr = a1;
                if (c == 3) mx = fmaxf(mx, fmaxf(fmaxf(a0, a1), a2));
            }
        }
        if (c == 3) amax = mx;

        p[c]      = ctr;
        p[16 + c] = (P0 - P2) * 0.0625f;
        p[32 + c] = (U0 - U2) * 0.0625f;
        p[48 + c] = (V0 - V2) * 0.0625f;

        if (c + 1 < C) {
            float* nb = tile[(c + 1) & 1];
            nb[s0i] = r0;
            if (wr1) nb[s1i] = r1;
        }
        __syncthreads();
    }

    float delta[C];
#pragma unroll
    for (int c = 0; c < C; ++c) delta[c] = 0.f;

    // Fused MLP from LDS weights. All reads are same-address ds_read_b128
    // broadcasts. Summation order identical to previous version.
    const float4* w1q  = (const float4*)lw1;
    const float4* w2tq = (const float4*)lw2t;
#pragma unroll 2
    for (int y = 0; y < HID; ++y) {
        float h0 = lb1[y], h1 = 0.f, h2 = 0.f, h3 = 0.f; // 4 chains, 16-deep
#pragma unroll
        for (int j = 0; j < 16; ++j) {
            const float4 w = w1q[(y << 4) + j];
            h0 = fmaf(w.x, p[4 * j],     h0);
            h1 = fmaf(w.y, p[4 * j + 1], h1);
            h2 = fmaf(w.z, p[4 * j + 2], h2);
            h3 = fmaf(w.w, p[4 * j + 3], h3);
        }
        const float h = fmaxf((h0 + h1) + (h2 + h3), 0.f);
#pragma unroll
        for (int j = 0; j < 4; ++j) {
            const float4 w = w2tq[(y << 2) + j];
            delta[4 * j]     = fmaf(w.x, h, delta[4 * j]);
            delta[4 * j + 1] = fmaf(w.y, h, delta[4 * j + 1]);
            delta[4 * j + 2] = fmaf(w.z, h, delta[4 * j + 2]);
            delta[4 * j + 3] = fmaf(w.w, h, delta[4 * j + 3]);
        }
    }

    const float m = (ru < 0.5f) ? 1.f : 0.f;

    float* ob = out + (size_t)n * C * G3;
#pragma unroll
    for (int c = 0; c < C; ++c) {
        // p[c] is the identity feature == old center value s0.
        ob[(size_t)c * G3 + vofs] = fmaf(delta[c], m, p[c]);
    }
    premask[(size_t)n * G3 + vofs] = (amax > 0.1f) ? 1.f : 0.f;
}

// ---------------------------------------------------------------------------
// Pass 2a: post-alive pooling on the NEW alpha (read-only on d_out),
// combine with pre-alive mask in-place in d_ws. No cross-thread hazards.
// ---------------------------------------------------------------------------
__global__ __launch_bounds__(256)
void nca_postmask(const float* __restrict__ newstate, float* __restrict__ mask)
{
    const int idx = blockIdx.x * 256 + threadIdx.x; // over NBATCH*G3
    const int n = idx >> 18;
    const int v = idx & (G3 - 1);
    const int x = v & 63, y = (v >> 6) & 63, z = v >> 12;
    const float* ab = newstate + ((size_t)n * C + 3) * G3;
    float mx = -3.0e38f;
#pragma unroll
    for (int dz = -1; dz <= 1; ++dz) {
        const int zz = min(max(z + dz, 0), G - 1);
#pragma unroll
        for (int dy = -1; dy <= 1; ++dy) {
            const int yy = min(max(y + dy, 0), G - 1);
            const int xm = max(x - 1, 0), xp = min(x + 1, G - 1);
            const float* row = ab + (size_t)zz * (G * G) + (size_t)yy * G;
            mx = fmaxf(mx, fmaxf(fmaxf(row[xm], row[x]), row[xp]));
        }
    }
    const float post = (mx > 0.1f) ? 1.f : 0.f;
    mask[idx] *= post;
}

// ---------------------------------------------------------------------------
// Pass 2b: out *= mask (broadcast over channels), float4-vectorized.
// ---------------------------------------------------------------------------
__global__ __launch_bounds__(256)
void nca_apply(float4* __restrict__ out4, const float4* __restrict__ mask4)
{
    const int idx = blockIdx.x * 256 + threadIdx.x; // over NBATCH*C*G3/4
    const size_t base = (size_t)idx * 4;
    const int n = (int)(base >> 22);          // C*G3 = 2^22
    const int v = (int)(base & (G3 - 1));     // G3 = 2^18
    const float4 m = mask4[((size_t)n * G3 + v) >> 2];
    float4 o = out4[idx];
    o.x *= m.x; o.y *= m.y; o.z *= m.z; o.w *= m.w;
    out4[idx] = o;
}

extern "C" void kernel_launch(void* const* d_in, const int* in_sizes, int n_in,
                              void* d_out, int out_size, void* d_ws, size_t ws_size,
                              hipStream_t stream)
{
    const float* state  = (const float*)d_in[0];
    const float* rand_u = (const float*)d_in[1];
    const float* w1     = (const float*)d_in[2];
    const float* b1     = (const float*)d_in[3];
    const float* w2     = (const float*)d_in[4];
    float* out  = (float*)d_out;
    float* mask = (float*)d_ws; // NBATCH*G3 floats = 4 MiB scratch

    nca_update  <<<NBATCH * 8 * 8 * 8, 512, 0, stream>>>(state, rand_u, w1, b1, w2, out, mask);
    nca_postmask<<<(NBATCH * G3) / 256, 256, 0, stream>>>(out, mask);
    nca_apply   <<<(NBATCH * C * G3 / 4) / 256, 256, 0, stream>>>((float4*)out, (const float4*)mask);
}

// Round 4
// 846.645 us; speedup vs baseline: 1.2066x; 1.2066x over previous
//
#include <hip/hip_runtime.h>

constexpr int G = 64;
constexpr int C = 16;
constexpr int NBATCH = 4;
constexpr int HID = 96;
constexpr int G3 = G * G * G; // 262144 = 2^18

// ---------------------------------------------------------------------------
// Pass 1: perception (edge-padded sobel stencil) + fused MLP + stochastic
// update.
//
// R4 change: __launch_bounds__(512, 4) was the bug. The backend treated
// min-4-waves/EU as an occupancy target and capped VGPRs at 64, spilling
// p[64]+delta[16] to scratch -> 2.2 GB/dispatch of HBM spill traffic
// (WRITE_SIZE 1.27 GB vs ~70 MB ideal) in R3, and 454 MB already in R2.
// Plain __launch_bounds__(512) lets the allocator keep the feature vector
// in registers (~110 VGPR -> still 4 waves/EU, 2 blocks/CU by LDS).
// Keeps: per-channel double-buffered tile staging (8 KB), LDS-broadcast
// weights (kills scalar-K$ streaming; ds_read_b128 same-address broadcast
// is conflict-free), halo strides 12/120 for 2-way-free bank access.
// One 8x8x8 voxel tile per block, 512 threads, 1 voxel/thread.
// ---------------------------------------------------------------------------
constexpr int W1_F = HID * 64;   // 6144 floats
constexpr int W2_F = HID * 16;   // 1536 floats, transposed [y][c]
constexpr int SY = 12;           // halo row stride
constexpr int SZ = 120;          // halo plane stride
constexpr int TILE_F = 10 * SZ;  // 1200

__global__ __launch_bounds__(512)
void nca_update(const float* __restrict__ state, const float* __restrict__ rand_u,
                const float* __restrict__ w1, const float* __restrict__ b1,
                const float* __restrict__ w2,
                float* __restrict__ out, float* __restrict__ premask)
{
    __shared__ float lw1[W1_F];      // 24576 B
    __shared__ float lb1[HID];       //   384 B
    __shared__ float lw2t[W2_F];     //  6144 B
    __shared__ float tile[2][TILE_F];//  9600 B   -> 40.7 KB total

    const int tid = threadIdx.x;
    const int bid = blockIdx.x;
    const int bx = bid & 7, by = (bid >> 3) & 7, bz = (bid >> 6) & 7, n = bid >> 9;
    const int x0 = bx * 8, y0 = by * 8, z0 = bz * 8;
    const float* sb = state + (size_t)n * C * G3;

    // --- one-time weight staging (w1/w2 are L2-resident after first blocks) ---
    for (int i = tid; i < W1_F; i += 512) lw1[i] = w1[i];
    if (tid < HID) lb1[tid] = b1[tid];
    for (int i = tid; i < W2_F; i += 512) lw2t[i] = w2[(i & 15) * HID + (i >> 4)];

    // --- halo source offsets + LDS targets (identical every channel) ---
    const int i0 = tid;
    const int i1 = tid + 512;
    const bool wr1 = (i1 < 1000);
    int vo0, vo1, s0i, s1i;
    {
        int lx = i0 % 10, t = i0 / 10;
        int ly = t % 10, lz = t / 10;
        s0i = lz * SZ + ly * SY + lx;
        int gx = min(max(x0 + lx - 1, 0), G - 1);
        int gy = min(max(y0 + ly - 1, 0), G - 1);
        int gz = min(max(z0 + lz - 1, 0), G - 1);
        vo0 = gz * (G * G) + gy * G + gx;
    }
    {
        int j = min(i1, 999);
        int lx = j % 10, t = j / 10;
        int ly = t % 10, lz = t / 10;
        s1i = lz * SZ + ly * SY + lx;
        int gx = min(max(x0 + lx - 1, 0), G - 1);
        int gy = min(max(y0 + ly - 1, 0), G - 1);
        int gz = min(max(z0 + lz - 1, 0), G - 1);
        vo1 = gz * (G * G) + gy * G + gx;
    }

    // Per-voxel rand load issued early; consumed only at the end.
    const int lxl = (tid & 7) + 1, lyl = ((tid >> 3) & 7) + 1, lzl = (tid >> 6) + 1;
    const int gx = x0 + lxl - 1, gy = y0 + lyl - 1, gz = z0 + lzl - 1;
    const size_t vofs = (size_t)gz * (G * G) + (size_t)gy * G + gx;
    const float ru = rand_u[(size_t)n * G3 + vofs];

    // Stage channel 0.
    tile[0][s0i] = sb[vo0];
    if (wr1) tile[0][s1i] = sb[vo1];
    __syncthreads(); // also covers weight staging

    const int cbase = (lzl - 1) * SZ + (lyl - 1) * SY + (lxl - 1);

    // Perception features; layout matches w1 columns: x = k*16 + c.
    float p[64];
    float amax = -3.0e38f;

#pragma unroll
    for (int c = 0; c < C; ++c) {
        // Prefetch next channel (HBM latency hides under the stencil).
        float r0 = 0.f, r1 = 0.f;
        if (c + 1 < C) {
            r0 = sb[(size_t)(c + 1) * G3 + vo0];
            r1 = sb[(size_t)(c + 1) * G3 + vo1];
        }

        const float* buf = tile[c & 1];
        float P0 = 0.f, P2 = 0.f, U0 = 0.f, U2 = 0.f, V0 = 0.f, V2 = 0.f;
        float ctr = 0.f, mx = -3.0e38f;
#pragma unroll
        for (int dz = 0; dz < 3; ++dz) {
            const float gzw = (dz == 1) ? 2.f : 1.f;
#pragma unroll
            for (int dy = 0; dy < 3; ++dy) {
                const float gyw = (dy == 1) ? 2.f : 1.f;
                const float* r = buf + cbase + dz * SZ + dy * SY;
                const float a0 = r[0], a1 = r[1], a2 = r[2];
                const float rs = a0 + 2.f * a1 + a2;
                if (dz == 0) P0 += gyw * rs;
                if (dz == 2) P2 += gyw * rs;
                if (dy == 0) U0 += gzw * rs;
                if (dy == 2) U2 += gzw * rs;
                V0 += gzw * gyw * a0;
                V2 += gzw * gyw * a2;
                if (dz == 1 && dy == 1) ctr = a1;
                if (c == 3) mx = fmaxf(mx, fmaxf(fmaxf(a0, a1), a2));
            }
        }
        if (c == 3) amax = mx;

        p[c]      = ctr;
        p[16 + c] = (P0 - P2) * 0.0625f;
        p[32 + c] = (U0 - U2) * 0.0625f;
        p[48 + c] = (V0 - V2) * 0.0625f;

        if (c + 1 < C) {
            float* nb = tile[(c + 1) & 1];
            nb[s0i] = r0;
            if (wr1) nb[s1i] = r1;
        }
        __syncthreads();
    }

    float delta[C];
#pragma unroll
    for (int c = 0; c < C; ++c) delta[c] = 0.f;

    // Fused MLP from LDS weights. All reads are same-address ds_read_b128
    // broadcasts. Summation order identical to previous versions.
    const float4* w1q  = (const float4*)lw1;
    const float4* w2tq = (const float4*)lw2t;
#pragma unroll 2
    for (int y = 0; y < HID; ++y) {
        float h0 = lb1[y], h1 = 0.f, h2 = 0.f, h3 = 0.f; // 4 chains, 16-deep
#pragma unroll
        for (int j = 0; j < 16; ++j) {
            const float4 w = w1q[(y << 4) + j];
            h0 = fmaf(w.x, p[4 * j],     h0);
            h1 = fmaf(w.y, p[4 * j + 1], h1);
            h2 = fmaf(w.z, p[4 * j + 2], h2);
            h3 = fmaf(w.w, p[4 * j + 3], h3);
        }
        const float h = fmaxf((h0 + h1) + (h2 + h3), 0.f);
#pragma unroll
        for (int j = 0; j < 4; ++j) {
            const float4 w = w2tq[(y << 2) + j];
            delta[4 * j]     = fmaf(w.x, h, delta[4 * j]);
            delta[4 * j + 1] = fmaf(w.y, h, delta[4 * j + 1]);
            delta[4 * j + 2] = fmaf(w.z, h, delta[4 * j + 2]);
            delta[4 * j + 3] = fmaf(w.w, h, delta[4 * j + 3]);
        }
    }

    const float m = (ru < 0.5f) ? 1.f : 0.f;

    float* ob = out + (size_t)n * C * G3;
#pragma unroll
    for (int c = 0; c < C; ++c) {
        // p[c] is the identity feature == old center value s0.
        ob[(size_t)c * G3 + vofs] = fmaf(delta[c], m, p[c]);
    }
    premask[(size_t)n * G3 + vofs] = (amax > 0.1f) ? 1.f : 0.f;
}

// ---------------------------------------------------------------------------
// Pass 2a: post-alive pooling on the NEW alpha (read-only on d_out),
// combine with pre-alive mask in-place in d_ws. No cross-thread hazards.
// ---------------------------------------------------------------------------
__global__ __launch_bounds__(256)
void nca_postmask(const float* __restrict__ newstate, float* __restrict__ mask)
{
    const int idx = blockIdx.x * 256 + threadIdx.x; // over NBATCH*G3
    const int n = idx >> 18;
    const int v = idx & (G3 - 1);
    const int x = v & 63, y = (v >> 6) & 63, z = v >> 12;
    const float* ab = newstate + ((size_t)n * C + 3) * G3;
    float mx = -3.0e38f;
#pragma unroll
    for (int dz = -1; dz <= 1; ++dz) {
        const int zz = min(max(z + dz, 0), G - 1);
#pragma unroll
        for (int dy = -1; dy <= 1; ++dy) {
            const int yy = min(max(y + dy, 0), G - 1);
            const int xm = max(x - 1, 0), xp = min(x + 1, G - 1);
            const float* row = ab + (size_t)zz * (G * G) + (size_t)yy * G;
            mx = fmaxf(mx, fmaxf(fmaxf(row[xm], row[x]), row[xp]));
        }
    }
    const float post = (mx > 0.1f) ? 1.f : 0.f;
    mask[idx] *= post;
}

// ---------------------------------------------------------------------------
// Pass 2b: out *= mask (broadcast over channels), float4-vectorized.
// ---------------------------------------------------------------------------
__global__ __launch_bounds__(256)
void nca_apply(float4* __restrict__ out4, const float4* __restrict__ mask4)
{
    const int idx = blockIdx.x * 256 + threadIdx.x; // over NBATCH*C*G3/4
    const size_t base = (size_t)idx * 4;
    const int n = (int)(base >> 22);          // C*G3 = 2^22
    const int v = (int)(base & (G3 - 1));     // G3 = 2^18
    const float4 m = mask4[((size_t)n * G3 + v) >> 2];
    float4 o = out4[idx];
    o.x *= m.x; o.y *= m.y; o.z *= m.z; o.w *= m.w;
    out4[idx] = o;
}

extern "C" void kernel_launch(void* const* d_in, const int* in_sizes, int n_in,
                              void* d_out, int out_size, void* d_ws, size_t ws_size,
                              hipStream_t stream)
{
    const float* state  = (const float*)d_in[0];
    const float* rand_u = (const float*)d_in[1];
    const float* w1     = (const float*)d_in[2];
    const float* b1     = (const float*)d_in[3];
    const float* w2     = (const float*)d_in[4];
    float* out  = (float*)d_out;
    float* mask = (float*)d_ws; // NBATCH*G3 floats = 4 MiB scratch

    nca_update  <<<NBATCH * 8 * 8 * 8, 512, 0, stream>>>(state, rand_u, w1, b1, w2, out, mask);
    nca_postmask<<<(NBATCH * G3) / 256, 256, 0, stream>>>(out, mask);
    nca_apply   <<<(NBATCH * C * G3 / 4) / 256, 256, 0, stream>>>((float4*)out, (const float4*)mask);
}

// Round 5
// 843.307 us; speedup vs baseline: 1.2114x; 1.0040x over previous
//
#include <hip/hip_runtime.h>

constexpr int G = 64;
constexpr int C = 16;
constexpr int NBATCH = 4;
constexpr int HID = 96;
constexpr int G3 = G * G * G; // 262144 = 2^18

// ---------------------------------------------------------------------------
// Pass 1: perception (edge-padded sobel stencil) + fused MLP + stochastic
// update.
//
// R5: merge the two proven-good structures and drop the proven-bad ones.
//  - R1 proved: scalar (wave-uniform) weight loads -> weights live in the
//    SGPR file, zero VGPR pressure, zero spill traffic (84 VGPR, 179/70 MB
//    = exactly ideal HBM traffic).
//  - R2 proved: per-channel double-buffered 9.6 KB tile -> 2+ blocks/CU.
//  - R3/R4 proved: LDS-staged float4 weights are a regression — each
//    ds_read_b128 costs 4 VGPR temps, the scheduler hoists them to hide
//    latency, and p[64] spills to scratch (WRITE_SIZE 10x ideal even at
//    128 VGPRs). Also __launch_bounds__(512,4) caps VGPR at 64 -> spills.
// One 8x8x8 voxel tile per block, 512 threads, 1 voxel/thread.
// ---------------------------------------------------------------------------
constexpr int SY = 12;           // halo row stride (2-way bank aliasing = free)
constexpr int SZ = 120;          // halo plane stride
constexpr int TILE_F = 10 * SZ;  // 1200 floats per channel buffer

__global__ __launch_bounds__(512)
void nca_update(const float* __restrict__ state, const float* __restrict__ rand_u,
                const float* __restrict__ w1, const float* __restrict__ b1,
                const float* __restrict__ w2,
                float* __restrict__ out, float* __restrict__ premask)
{
    __shared__ float tile[2][TILE_F]; // 9600 B total

    const int tid = threadIdx.x;
    const int bid = blockIdx.x;
    const int bx = bid & 7, by = (bid >> 3) & 7, bz = (bid >> 6) & 7, n = bid >> 9;
    const int x0 = bx * 8, y0 = by * 8, z0 = bz * 8;
    const float* sb = state + (size_t)n * C * G3;

    // --- halo source offsets + LDS targets (identical for every channel) ---
    const int i0 = tid;
    const int i1 = tid + 512;
    const bool wr1 = (i1 < 1000);
    int vo0, vo1, s0i, s1i;
    {
        int lx = i0 % 10, t = i0 / 10;
        int ly = t % 10, lz = t / 10;
        s0i = lz * SZ + ly * SY + lx;
        int gx = min(max(x0 + lx - 1, 0), G - 1);
        int gy = min(max(y0 + ly - 1, 0), G - 1);
        int gz = min(max(z0 + lz - 1, 0), G - 1);
        vo0 = gz * (G * G) + gy * G + gx;
    }
    {
        int j = min(i1, 999);
        int lx = j % 10, t = j / 10;
        int ly = t % 10, lz = t / 10;
        s1i = lz * SZ + ly * SY + lx;
        int gx = min(max(x0 + lx - 1, 0), G - 1);
        int gy = min(max(y0 + ly - 1, 0), G - 1);
        int gz = min(max(z0 + lz - 1, 0), G - 1);
        vo1 = gz * (G * G) + gy * G + gx;
    }

    // Per-voxel rand load issued early; consumed only at the end.
    const int lxl = (tid & 7) + 1, lyl = ((tid >> 3) & 7) + 1, lzl = (tid >> 6) + 1;
    const int gx = x0 + lxl - 1, gy = y0 + lyl - 1, gz = z0 + lzl - 1;
    const size_t vofs = (size_t)gz * (G * G) + (size_t)gy * G + gx;
    const float ru = rand_u[(size_t)n * G3 + vofs];

    // Stage channel 0.
    tile[0][s0i] = sb[vo0];
    if (wr1) tile[0][s1i] = sb[vo1];
    __syncthreads();

    const int cbase = (lzl - 1) * SZ + (lyl - 1) * SY + (lxl - 1);

    // Perception features; layout matches w1 columns: x = k*16 + c
    // (k: 0=identity, 1=sobel-z, 2=sobel-y, 3=sobel-x).
    float p[64];
    float amax = -3.0e38f;

#pragma unroll
    for (int c = 0; c < C; ++c) {
        // Prefetch next channel (HBM latency hides under the stencil).
        float r0 = 0.f, r1 = 0.f;
        if (c + 1 < C) {
            r0 = sb[(size_t)(c + 1) * G3 + vo0];
            r1 = sb[(size_t)(c + 1) * G3 + vo1];
        }

        const float* buf = tile[c & 1];
        float P0 = 0.f, P2 = 0.f, U0 = 0.f, U2 = 0.f, V0 = 0.f, V2 = 0.f;
        float ctr = 0.f, mx = -3.0e38f;
#pragma unroll
        for (int dz = 0; dz < 3; ++dz) {
            const float gzw = (dz == 1) ? 2.f : 1.f;
#pragma unroll
            for (int dy = 0; dy < 3; ++dy) {
                const float gyw = (dy == 1) ? 2.f : 1.f;
                const float* r = buf + cbase + dz * SZ + dy * SY;
                const float a0 = r[0], a1 = r[1], a2 = r[2];
                const float rs = a0 + 2.f * a1 + a2;
                if (dz == 0) P0 += gyw * rs;
                if (dz == 2) P2 += gyw * rs;
                if (dy == 0) U0 += gzw * rs;
                if (dy == 2) U2 += gzw * rs;
                V0 += gzw * gyw * a0;
                V2 += gzw * gyw * a2;
                if (dz == 1 && dy == 1) ctr = a1;
                if (c == 3) mx = fmaxf(mx, fmaxf(fmaxf(a0, a1), a2));
            }
        }
        if (c == 3) amax = mx;

        p[c]      = ctr;
        p[16 + c] = (P0 - P2) * 0.0625f;
        p[32 + c] = (U0 - U2) * 0.0625f;
        p[48 + c] = (V0 - V2) * 0.0625f;

        if (c + 1 < C) {
            float* nb = tile[(c + 1) & 1];
            nb[s0i] = r0;
            if (wr1) nb[s1i] = r1;
        }
        __syncthreads();
    }

    float delta[C];
#pragma unroll
    for (int c = 0; c < C; ++c) delta[c] = 0.f;

    // Fused MLP. All weight reads are wave-uniform -> compiler emits batched
    // s_load into the SGPR file: zero VGPR pressure (R1 proved no spills).
#pragma unroll 2
    for (int y = 0; y < HID; ++y) {
        const float* wr = w1 + y * 64;
        float h0 = b1[y], h1 = 0.f, h2 = 0.f, h3 = 0.f; // 4 chains, 16-deep each
#pragma unroll
        for (int x = 0; x < 64; x += 4) {
            h0 = fmaf(wr[x],     p[x],     h0);
            h1 = fmaf(wr[x + 1], p[x + 1], h1);
            h2 = fmaf(wr[x + 2], p[x + 2], h2);
            h3 = fmaf(wr[x + 3], p[x + 3], h3);
        }
        const float h = fmaxf((h0 + h1) + (h2 + h3), 0.f);
#pragma unroll
        for (int c = 0; c < C; ++c) delta[c] = fmaf(w2[c * HID + y], h, delta[c]);
    }

    const float m = (ru < 0.5f) ? 1.f : 0.f;

    float* ob = out + (size_t)n * C * G3;
#pragma unroll
    for (int c = 0; c < C; ++c) {
        // p[c] is the identity feature == old center value s0.
        ob[(size_t)c * G3 + vofs] = fmaf(delta[c], m, p[c]);
    }
    premask[(size_t)n * G3 + vofs] = (amax > 0.1f) ? 1.f : 0.f;
}

// ---------------------------------------------------------------------------
// Pass 2a: post-alive pooling on the NEW alpha (read-only on d_out),
// combine with pre-alive mask in-place in d_ws. No cross-thread hazards.
// ---------------------------------------------------------------------------
__global__ __launch_bounds__(256)
void nca_postmask(const float* __restrict__ newstate, float* __restrict__ mask)
{
    const int idx = blockIdx.x * 256 + threadIdx.x; // over NBATCH*G3
    const int n = idx >> 18;
    const int v = idx & (G3 - 1);
    const int x = v & 63, y = (v >> 6) & 63, z = v >> 12;
    const float* ab = newstate + ((size_t)n * C + 3) * G3;
    float mx = -3.0e38f;
#pragma unroll
    for (int dz = -1; dz <= 1; ++dz) {
        const int zz = min(max(z + dz, 0), G - 1);
#pragma unroll
        for (int dy = -1; dy <= 1; ++dy) {
            const int yy = min(max(y + dy, 0), G - 1);
            const int xm = max(x - 1, 0), xp = min(x + 1, G - 1);
            const float* row = ab + (size_t)zz * (G * G) + (size_t)yy * G;
            mx = fmaxf(mx, fmaxf(fmaxf(row[xm], row[x]), row[xp]));
        }
    }
    const float post = (mx > 0.1f) ? 1.f : 0.f;
    mask[idx] *= post;
}

// ---------------------------------------------------------------------------
// Pass 2b: out *= mask (broadcast over channels), float4-vectorized.
// ---------------------------------------------------------------------------
__global__ __launch_bounds__(256)
void nca_apply(float4* __restrict__ out4, const float4* __restrict__ mask4)
{
    const int idx = blockIdx.x * 256 + threadIdx.x; // over NBATCH*C*G3/4
    const size_t base = (size_t)idx * 4;
    const int n = (int)(base >> 22);          // C*G3 = 2^22
    const int v = (int)(base & (G3 - 1));     // G3 = 2^18
    const float4 m = mask4[((size_t)n * G3 + v) >> 2];
    float4 o = out4[idx];
    o.x *= m.x; o.y *= m.y; o.z *= m.z; o.w *= m.w;
    out4[idx] = o;
}

extern "C" void kernel_launch(void* const* d_in, const int* in_sizes, int n_in,
                              void* d_out, int out_size, void* d_ws, size_t ws_size,
                              hipStream_t stream)
{
    const float* state  = (const float*)d_in[0];
    const float* rand_u = (const float*)d_in[1];
    const float* w1     = (const float*)d_in[2];
    const float* b1     = (const float*)d_in[3];
    const float* w2     = (const float*)d_in[4];
    float* out  = (float*)d_out;
    float* mask = (float*)d_ws; // NBATCH*G3 floats = 4 MiB scratch

    nca_update  <<<NBATCH * 8 * 8 * 8, 512, 0, stream>>>(state, rand_u, w1, b1, w2, out, mask);
    nca_postmask<<<(NBATCH * G3) / 256, 256, 0, stream>>>(out, mask);
    nca_apply   <<<(NBATCH * C * G3 / 4) / 256, 256, 0, stream>>>((float4*)out, (const float4*)mask);
}